// Round 8
// baseline (227.670 us; speedup 1.0000x reference)
//
#include <hip/hip_runtime.h>
#include <hip/hip_bf16.h>

typedef __bf16 bf16_t;
typedef __bf16 bf16x8 __attribute__((ext_vector_type(8)));
typedef float f32x4 __attribute__((ext_vector_type(4)));
typedef short short4v __attribute__((ext_vector_type(4)));

#define D_MODEL 1024
#define T_SEQ 2048
#define NH 16
#define DKD 64
#define X_ELEMS (4194304u)   // 2*2048*1024
#define W_ELEMS (1048576u)   // 1024*1024
// 0.125 * log2(e): folds the 1/sqrt(dk) scale AND the exp->exp2 conversion into Q
#define Q_SCALE 0.18033688011112042f

__device__ __forceinline__ void async16(const bf16_t* g, bf16_t* l) {
    __builtin_amdgcn_global_load_lds((const __attribute__((address_space(1))) void*)g,
                                     (__attribute__((address_space(3))) void*)l, 16, 0, 0);
}

// ---------------- fp32 -> bf16 conversion for x + 4 weights ----------------
__global__ __launch_bounds__(256) void convert_kernel(
    const float* __restrict__ x, const float* __restrict__ wq,
    const float* __restrict__ wk, const float* __restrict__ wv,
    const float* __restrict__ wo,
    bf16_t* __restrict__ xb, bf16_t* __restrict__ wqb, bf16_t* __restrict__ wkb,
    bf16_t* __restrict__ wvb, bf16_t* __restrict__ wob)
{
    size_t idx = ((size_t)blockIdx.x * 256 + threadIdx.x) * 4;
    const float* src; bf16_t* dst; size_t off;
    if (idx < X_ELEMS) { src = x; dst = xb; off = idx; }
    else {
        size_t r = idx - X_ELEMS;
        unsigned w = (unsigned)(r >> 20);
        off = r & (W_ELEMS - 1);
        src = (w == 0) ? wq : (w == 1) ? wk : (w == 2) ? wv : wo;
        dst = (w == 0) ? wqb : (w == 1) ? wkb : (w == 2) ? wvb : wob;
    }
    float4 v = *(const float4*)(src + off);
    union { bf16_t b[4]; short4v s; } u;
    u.b[0] = (bf16_t)v.x; u.b[1] = (bf16_t)v.y;
    u.b[2] = (bf16_t)v.z; u.b[3] = (bf16_t)v.w;
    *(short4v*)(dst + off) = u.s;
}

// ---------------- RoPE cos/sin tables: [T][32] ----------------
__global__ __launch_bounds__(256) void rope_kernel(float* __restrict__ cost, float* __restrict__ sint)
{
    int idx = blockIdx.x * 256 + threadIdx.x;  // < 2048*32
    int t = idx >> 5, i = idx & 31;
    float inv = expf(-0.28782313662425572f * (float)i);  // 10000^(-i/32)
    float ang = (float)t * inv;
    float s, c;
    sincosf(ang, &s, &c);
    cost[idx] = c; sint[idx] = s;
}

// ---------------- GEMM C[m,n] = sum_k A[m,k]*W[n,k]  (m97 structure) ----------------
// mode 0: Q out (rope, *Q_SCALE)   mode 1: K out (rope)
// mode 2: V^T out (swapped operands so C/D col = token)
// mode 3: fp32 out [M,N], K split by blockIdx.z: z=0 -> fout, z=1 -> fpart
__global__ __launch_bounds__(256) void gemm_fused(
    const bf16_t* __restrict__ A,
    const bf16_t* __restrict__ W0, const bf16_t* __restrict__ W1, const bf16_t* __restrict__ W2,
    bf16_t* __restrict__ qout, bf16_t* __restrict__ kout, bf16_t* __restrict__ vout,
    const float* __restrict__ cost, const float* __restrict__ sint,
    float* __restrict__ fout, float* __restrict__ fpart, int modeBase)
{
    __shared__ bf16_t As[128 * 32];
    __shared__ bf16_t Bs[128 * 32];
    const int tid = threadIdx.x;
    const int wave = tid >> 6, lane = tid & 63;
    const int quad = lane >> 4, l16 = lane & 15;
    const int m0 = blockIdx.x * 128;
    const int n0 = blockIdx.y * 128;
    const int wm = (wave >> 1) * 64, wn = (wave & 1) * 64;
    const int mode = (modeBase == 3) ? 3 : (modeBase + blockIdx.z);
    const int kz = (modeBase == 3) ? blockIdx.z : 0;
    const int kBeg = kz * 512;
    const int kEnd = (modeBase == 3) ? (kBeg + 512) : 1024;
    const bf16_t* W = (mode == 1) ? W1 : (mode == 2) ? W2 : W0;

    const bf16_t* Afrag = (mode == 2) ? Bs : As;
    const bf16_t* Bfrag = (mode == 2) ? As : Bs;
    const int aoff = (mode == 2) ? wn : wm;
    const int boff = (mode == 2) ? wm : wn;

    const f32x4 fzero = {0.f, 0.f, 0.f, 0.f};
    f32x4 acc[4][4];
    #pragma unroll
    for (int i = 0; i < 4; ++i)
        #pragma unroll
        for (int j = 0; j < 4; ++j) acc[i][j] = fzero;

    for (int k0 = kBeg; k0 < kEnd; k0 += 32) {
        __syncthreads();
        #pragma unroll
        for (int c = 0; c < 2; ++c) {
            int G = c * 256 + tid;
            int row = G >> 2, go = G & 3;
            async16(A + (size_t)(m0 + row) * 1024 + (k0 + go * 8), As + (size_t)(c * 256 + wave * 64) * 8);
            async16(W + (size_t)(n0 + row) * 1024 + (k0 + go * 8), Bs + (size_t)(c * 256 + wave * 64) * 8);
        }
        __syncthreads();
        bf16x8 af[4], bfv[4];
        #pragma unroll
        for (int mi = 0; mi < 4; ++mi)
            af[mi] = *(const bf16x8*)(Afrag + (aoff + mi * 16 + l16) * 32 + quad * 8);
        #pragma unroll
        for (int ni = 0; ni < 4; ++ni)
            bfv[ni] = *(const bf16x8*)(Bfrag + (boff + ni * 16 + l16) * 32 + quad * 8);
        #pragma unroll
        for (int mi = 0; mi < 4; ++mi)
            #pragma unroll
            for (int ni = 0; ni < 4; ++ni)
                acc[mi][ni] = __builtin_amdgcn_mfma_f32_16x16x32_bf16(af[mi], bfv[ni], acc[mi][ni], 0, 0, 0);
    }

    #pragma unroll
    for (int mi = 0; mi < 4; ++mi) {
        #pragma unroll
        for (int ni = 0; ni < 4; ++ni) {
            #pragma unroll
            for (int reg = 0; reg < 4; ++reg) {
                float v = acc[mi][ni][reg];
                if (mode == 2) {
                    int f   = n0 + wn + mi * 16 + quad * 4 + reg;
                    int tok = m0 + wm + ni * 16 + l16;
                    int t = tok & (T_SEQ - 1), b = tok >> 11;
                    int h = f >> 6, dk = f & 63;
                    vout[(((size_t)b * NH + h) * DKD + dk) * T_SEQ + t] = (bf16_t)v;
                } else {
                    int row = m0 + wm + mi * 16 + quad * 4 + reg;
                    int col = n0 + wn + ni * 16 + l16;
                    if (mode == 3) {
                        float* fo = kz ? fpart : fout;
                        fo[(size_t)row * D_MODEL + col] = v;
                    } else {
                        int t = row & (T_SEQ - 1), b = row >> 11;
                        int h = col >> 6, dk = col & 63;
                        float vp = __shfl_xor(v, 1);
                        int fi = dk >> 1;
                        float c = cost[t * 32 + fi], s = sint[t * 32 + fi];
                        float r = (dk & 1) ? (vp * s + v * c) : (v * c - vp * s);
                        if (mode == 0) r *= Q_SCALE;   // fold 1/sqrt(dk)*log2e into Q
                        bf16_t* dst = (mode == 0) ? qout : kout;
                        dst[(((size_t)b * NH + h) * T_SEQ + t) * DKD + dk] = (bf16_t)r;
                    }
                }
            }
        }
    }
}

// ---------------- add partials: out += part ----------------
__global__ __launch_bounds__(256) void add_kernel(float* __restrict__ out, const float* __restrict__ part)
{
    size_t i = ((size_t)blockIdx.x * 256 + threadIdx.x) * 4;
    float4 o = *(const float4*)(out + i);
    float4 p = *(const float4*)(part + i);
    o.x += p.x; o.y += p.y; o.z += p.z; o.w += p.w;
    *(float4*)(out + i) = o;
}

// ---------------- flash attention: key-split x4 + max-free softmax ----------------
// 256-thread block = 4 waves sharing one 32-query range; wave w handles key
// tiles kt ≡ w (mod 4). Fixed-shift softmax (P=exp2(s), no running max) makes
// partial (O,l) combine a PURE SUM -> one LDS combine + single barrier.
// Critical chain: 33 -> <=9 tiles; ~16 waves/CU resident.
__global__ __launch_bounds__(256, 2) void attn_kernel(
    const bf16_t* __restrict__ Q, const bf16_t* __restrict__ Kb,
    const bf16_t* __restrict__ Vt, bf16_t* __restrict__ O)
{
    __shared__ float Ocomb[3][2][4][4][16][4];  // [w-1][j][di][quad][l16][reg]
    __shared__ float Lcomb[3][2][64];           // [w-1][j][lane]
    __shared__ bf16_t Pw[4][16 * 72];           // per-wave P^T buffer
    const int tid = threadIdx.x;
    const int wave = tid >> 6, lane = tid & 63;
    const int quad = lane >> 4, l16 = lane & 15;
    const int bh = blockIdx.x;
    const int qb = 63 - (int)blockIdx.y;        // heavy q-blocks dispatch first
    const int qw = qb * 32;

    const bf16_t* kbase = Kb + (size_t)bh * T_SEQ * DKD;
    const bf16_t* vbase = Vt + (size_t)bh * DKD * T_SEQ;

    // Q^T B-frags: n=l16 (query), k=quad*8+j (+32)
    bf16x8 qf[2][2];
    #pragma unroll
    for (int j = 0; j < 2; ++j) {
        const bf16_t* qp = Q + ((size_t)bh * T_SEQ + qw + j * 16 + l16) * DKD;
        qf[j][0] = *(const bf16x8*)(qp + quad * 8);
        qf[j][1] = *(const bf16x8*)(qp + 32 + quad * 8);
    }
    const f32x4 fzero = {0.f, 0.f, 0.f, 0.f};
    f32x4 oacc[2][4];
    #pragma unroll
    for (int j = 0; j < 2; ++j)
        #pragma unroll
        for (int i = 0; i < 4; ++i) oacc[j][i] = fzero;
    float lsum[2] = {0.f, 0.f};

    const int nkt = (qw + 95) >> 6;   // causal 64-key tile count for this q-block

    bf16x8 kcur[4][2], knxt[4][2], vcur[4][2];
    // initial K tile for kt = wave (rows <= 255 < T_SEQ: always safe to read)
    #pragma unroll
    for (int fi = 0; fi < 4; ++fi) {
        const bf16_t* kr = kbase + (size_t)(wave * 64 + fi * 16 + l16) * DKD + quad * 8;
        kcur[fi][0] = *(const bf16x8*)(kr);
        kcur[fi][1] = *(const bf16x8*)(kr + 32);
    }

    for (int kt = wave; kt < nkt; kt += 4) {
        const int k0 = kt * 64;
        // V^T frags: m=d (l16), k=key
        #pragma unroll
        for (int di = 0; di < 4; ++di) {
            const bf16_t* vr = vbase + (size_t)(di * 16 + l16) * T_SEQ + k0 + quad * 8;
            vcur[di][0] = *(const bf16x8*)(vr);
            vcur[di][1] = *(const bf16x8*)(vr + 32);
        }
        // prefetch this wave's next K tile
        if (kt + 4 < nkt) {
            #pragma unroll
            for (int fi = 0; fi < 4; ++fi) {
                const bf16_t* kr = kbase + (size_t)((kt + 4) * 64 + fi * 16 + l16) * DKD + quad * 8;
                knxt[fi][0] = *(const bf16x8*)(kr);
                knxt[fi][1] = *(const bf16x8*)(kr + 32);
            }
        }

        #pragma unroll
        for (int j = 0; j < 2; ++j) {
            if (k0 > qw + j * 16 + 15) continue;   // q-tile fully masked
            const int qcol = qw + j * 16 + l16;
            f32x4 s[4];
            #pragma unroll
            for (int fi = 0; fi < 4; ++fi) {
                f32x4 z = fzero;
                z = __builtin_amdgcn_mfma_f32_16x16x32_bf16(kcur[fi][0], qf[j][0], z, 0, 0, 0);
                z = __builtin_amdgcn_mfma_f32_16x16x32_bf16(kcur[fi][1], qf[j][1], z, 0, 0, 0);
                s[fi] = z;
            }
            if (k0 + 63 > qw + j * 16) {   // diagonal tile: causal mask
                #pragma unroll
                for (int fi = 0; fi < 4; ++fi)
                    #pragma unroll
                    for (int reg = 0; reg < 4; ++reg) {
                        int key = k0 + fi * 16 + quad * 4 + reg;
                        s[fi][reg] = (key > qcol) ? -__builtin_inff() : s[fi][reg];
                    }
            }
            float sm = 0.f;
            #pragma unroll
            for (int fi = 0; fi < 4; ++fi)
                #pragma unroll
                for (int reg = 0; reg < 4; ++reg) {
                    float p = __builtin_amdgcn_exp2f(s[fi][reg]);
                    s[fi][reg] = p;
                    sm += p;
                }
            lsum[j] += sm;

            // P^T: C/D -> wave-private LDS -> B-operand frags
            bf16_t* pw = &Pw[wave][0];
            #pragma unroll
            for (int fi = 0; fi < 4; ++fi) {
                union { bf16_t h[4]; unsigned long long u64; } pk;
                pk.h[0] = (bf16_t)s[fi][0]; pk.h[1] = (bf16_t)s[fi][1];
                pk.h[2] = (bf16_t)s[fi][2]; pk.h[3] = (bf16_t)s[fi][3];
                *(unsigned long long*)(pw + l16 * 72 + fi * 16 + quad * 4) = pk.u64;
            }
            bf16x8 pf[2];
            pf[0] = *(const bf16x8*)(pw + l16 * 72 + quad * 8);
            pf[1] = *(const bf16x8*)(pw + l16 * 72 + 32 + quad * 8);

            #pragma unroll
            for (int di = 0; di < 4; ++di) {
                oacc[j][di] = __builtin_amdgcn_mfma_f32_16x16x32_bf16(vcur[di][0], pf[0], oacc[j][di], 0, 0, 0);
                oacc[j][di] = __builtin_amdgcn_mfma_f32_16x16x32_bf16(vcur[di][1], pf[1], oacc[j][di], 0, 0, 0);
            }
        }

        if (kt + 4 < nkt) {
            #pragma unroll
            for (int fi = 0; fi < 4; ++fi) {
                kcur[fi][0] = knxt[fi][0];
                kcur[fi][1] = knxt[fi][1];
            }
        }
    }

    // combine partials: waves 1-3 write (O,l) to LDS; barrier; wave 0 sums
    if (wave > 0) {
        #pragma unroll
        for (int j = 0; j < 2; ++j) {
            #pragma unroll
            for (int di = 0; di < 4; ++di)
                *(f32x4*)&Ocomb[wave - 1][j][di][quad][l16][0] = oacc[j][di];
            Lcomb[wave - 1][j][lane] = lsum[j];
        }
    }
    __syncthreads();
    if (wave != 0) return;

    #pragma unroll
    for (int j = 0; j < 2; ++j) {
        #pragma unroll
        for (int w = 0; w < 3; ++w) {
            #pragma unroll
            for (int di = 0; di < 4; ++di) {
                f32x4 p = *(const f32x4*)&Ocomb[w][j][di][quad][l16][0];
                #pragma unroll
                for (int reg = 0; reg < 4; ++reg) oacc[j][di][reg] += p[reg];
            }
            lsum[j] += Lcomb[w][j][lane];
        }
    }

    // epilogue: cross-quad l reduction, scale + store
    const int b = bh >> 4, h = bh & 15;
    #pragma unroll
    for (int j = 0; j < 2; ++j) {
        float l = lsum[j];
        l += __shfl_xor(l, 16);
        l += __shfl_xor(l, 32);
        float rl = 1.0f / l;
        int q = qw + j * 16 + l16;
        #pragma unroll
        for (int di = 0; di < 4; ++di) {
            union { bf16_t hh[4]; unsigned long long u64; } ok;
            #pragma unroll
            for (int reg = 0; reg < 4; ++reg) ok.hh[reg] = (bf16_t)(oacc[j][di][reg] * rl);
            int d = di * 16 + quad * 4;
            *(unsigned long long*)(O + ((size_t)b * T_SEQ + q) * D_MODEL + h * DKD + d) = ok.u64;
        }
    }
}

extern "C" void kernel_launch(void* const* d_in, const int* in_sizes, int n_in,
                              void* d_out, int out_size, void* d_ws, size_t ws_size,
                              hipStream_t stream)
{
    const float* x  = (const float*)d_in[0];
    const float* wq = (const float*)d_in[1];
    const float* wk = (const float*)d_in[2];
    const float* wv = (const float*)d_in[3];
    const float* wo = (const float*)d_in[4];
    float* out = (float*)d_out;

    char* ws = (char*)d_ws;
    size_t off = 0;
    auto alloc = [&](size_t bytes) -> void* {
        void* p = ws + off; off += (bytes + 255) & ~(size_t)255; return p;
    };
    bf16_t* xb   = (bf16_t*)alloc((size_t)X_ELEMS * 2);
    bf16_t* wqb  = (bf16_t*)alloc((size_t)W_ELEMS * 2);
    bf16_t* wkb  = (bf16_t*)alloc((size_t)W_ELEMS * 2);
    bf16_t* wvb  = (bf16_t*)alloc((size_t)W_ELEMS * 2);
    bf16_t* wob  = (bf16_t*)alloc((size_t)W_ELEMS * 2);
    bf16_t* qb   = (bf16_t*)alloc((size_t)X_ELEMS * 2);
    bf16_t* kb   = (bf16_t*)alloc((size_t)X_ELEMS * 2);
    bf16_t* vtb  = (bf16_t*)alloc((size_t)X_ELEMS * 2);
    bf16_t* ob   = (bf16_t*)alloc((size_t)X_ELEMS * 2);
    float*  cost = (float*)alloc((size_t)T_SEQ * 32 * 4);
    float*  sint = (float*)alloc((size_t)T_SEQ * 32 * 4);
    // fp32 split-K partial for out-proj: aliases qb/kb (dead after attn)
    float*  fpart = (float*)qb;

    convert_kernel<<<8192, 256, 0, stream>>>(x, wq, wk, wv, wo, xb, wqb, wkb, wvb, wob);
    rope_kernel<<<256, 256, 0, stream>>>(cost, sint);
    gemm_fused<<<dim3(32, 8, 3), 256, 0, stream>>>(xb, wqb, wkb, wvb, qb, kb, vtb, cost, sint,
                                                   nullptr, nullptr, 0);
    attn_kernel<<<dim3(32, 64), 256, 0, stream>>>(qb, kb, vtb, ob);
    gemm_fused<<<dim3(32, 8, 2), 256, 0, stream>>>(ob, wob, nullptr, nullptr, nullptr, nullptr, nullptr,
                                                   cost, sint, out, fpart, 3);
    add_kernel<<<4096, 256, 0, stream>>>(out, fpart);
}

// Round 9
// 226.589 us; speedup vs baseline: 1.0048x; 1.0048x over previous
//
#include <hip/hip_runtime.h>
#include <hip/hip_bf16.h>

typedef __bf16 bf16_t;
typedef __bf16 bf16x8 __attribute__((ext_vector_type(8)));
typedef float f32x4 __attribute__((ext_vector_type(4)));
typedef short short4v __attribute__((ext_vector_type(4)));

#define D_MODEL 1024
#define T_SEQ 2048
#define NH 16
#define DKD 64
#define X_ELEMS (4194304u)   // 2*2048*1024
#define W_ELEMS (1048576u)   // 1024*1024
// 0.125 * log2(e): folds the 1/sqrt(dk) scale AND the exp->exp2 conversion into Q
#define Q_SCALE 0.18033688011112042f

__device__ __forceinline__ void async16(const bf16_t* g, bf16_t* l) {
    __builtin_amdgcn_global_load_lds((const __attribute__((address_space(1))) void*)g,
                                     (__attribute__((address_space(3))) void*)l, 16, 0, 0);
}

// ---------------- fp32 -> bf16 conversion for x + 4 weights ----------------
__global__ __launch_bounds__(256) void convert_kernel(
    const float* __restrict__ x, const float* __restrict__ wq,
    const float* __restrict__ wk, const float* __restrict__ wv,
    const float* __restrict__ wo,
    bf16_t* __restrict__ xb, bf16_t* __restrict__ wqb, bf16_t* __restrict__ wkb,
    bf16_t* __restrict__ wvb, bf16_t* __restrict__ wob)
{
    size_t idx = ((size_t)blockIdx.x * 256 + threadIdx.x) * 4;
    const float* src; bf16_t* dst; size_t off;
    if (idx < X_ELEMS) { src = x; dst = xb; off = idx; }
    else {
        size_t r = idx - X_ELEMS;
        unsigned w = (unsigned)(r >> 20);
        off = r & (W_ELEMS - 1);
        src = (w == 0) ? wq : (w == 1) ? wk : (w == 2) ? wv : wo;
        dst = (w == 0) ? wqb : (w == 1) ? wkb : (w == 2) ? wvb : wob;
    }
    float4 v = *(const float4*)(src + off);
    union { bf16_t b[4]; short4v s; } u;
    u.b[0] = (bf16_t)v.x; u.b[1] = (bf16_t)v.y;
    u.b[2] = (bf16_t)v.z; u.b[3] = (bf16_t)v.w;
    *(short4v*)(dst + off) = u.s;
}

// ---------------- RoPE cos/sin tables: [T][32] ----------------
__global__ __launch_bounds__(256) void rope_kernel(float* __restrict__ cost, float* __restrict__ sint)
{
    int idx = blockIdx.x * 256 + threadIdx.x;  // < 2048*32
    int t = idx >> 5, i = idx & 31;
    float inv = expf(-0.28782313662425572f * (float)i);  // 10000^(-i/32)
    float ang = (float)t * inv;
    float s, c;
    sincosf(ang, &s, &c);
    cost[idx] = c; sint[idx] = s;
}

// ---------------- GEMM core: C[m,n] = sum_k A[m,k]*W[n,k], BK=64, XOR-swizzled LDS ----------------
// LDS rows are 64 elems (128 B): granule position p of row r holds global granule p^(r&7)
// (same verified pattern as the attention staging). Row-linear layout keeps the
// global_load_lds lane-contiguity requirement intact.
// mode 0: Q out (rope, *Q_SCALE)  mode 1: K out (rope)
// mode 2: V^T out (swapped operands so C/D col = token)  mode 3: fp32 out [M,N]
__device__ __forceinline__ void gemm_body(
    int mode,
    const bf16_t* __restrict__ A, const bf16_t* __restrict__ W,
    bf16_t* __restrict__ qout, bf16_t* __restrict__ kout, bf16_t* __restrict__ vout,
    const float* __restrict__ cost, const float* __restrict__ sint,
    float* __restrict__ fout)
{
    __shared__ bf16_t As[128 * 64];
    __shared__ bf16_t Bs[128 * 64];
    const int tid = threadIdx.x;
    const int wave = tid >> 6, lane = tid & 63;
    const int quad = lane >> 4, l16 = lane & 15;
    const int m0 = blockIdx.x * 128;
    const int n0 = blockIdx.y * 128;
    const int wm = (wave >> 1) * 64, wn = (wave & 1) * 64;

    const bf16_t* Afrag = (mode == 2) ? Bs : As;
    const bf16_t* Bfrag = (mode == 2) ? As : Bs;
    const int aoff = (mode == 2) ? wn : wm;
    const int boff = (mode == 2) ? wm : wn;

    const f32x4 fzero = {0.f, 0.f, 0.f, 0.f};
    f32x4 acc[4][4];
    #pragma unroll
    for (int i = 0; i < 4; ++i)
        #pragma unroll
        for (int j = 0; j < 4; ++j) acc[i][j] = fzero;

    for (int k0 = 0; k0 < 1024; k0 += 64) {
        __syncthreads();
        #pragma unroll
        for (int c = 0; c < 4; ++c) {
            int G = c * 256 + tid;
            int row = G >> 3, p = G & 7;
            int go = p ^ (row & 7);
            async16(A + (size_t)(m0 + row) * 1024 + (k0 + go * 8), As + (size_t)(c * 256 + wave * 64) * 8);
            async16(W + (size_t)(n0 + row) * 1024 + (k0 + go * 8), Bs + (size_t)(c * 256 + wave * 64) * 8);
        }
        __syncthreads();
        #pragma unroll
        for (int ks = 0; ks < 2; ++ks) {
            bf16x8 af[4], bfv[4];
            #pragma unroll
            for (int mi = 0; mi < 4; ++mi) {
                int r = aoff + mi * 16 + l16;
                af[mi] = *(const bf16x8*)(Afrag + r * 64 + (((ks * 4 + quad) ^ (r & 7)) * 8));
            }
            #pragma unroll
            for (int ni = 0; ni < 4; ++ni) {
                int r = boff + ni * 16 + l16;
                bfv[ni] = *(const bf16x8*)(Bfrag + r * 64 + (((ks * 4 + quad) ^ (r & 7)) * 8));
            }
            #pragma unroll
            for (int mi = 0; mi < 4; ++mi)
                #pragma unroll
                for (int ni = 0; ni < 4; ++ni)
                    acc[mi][ni] = __builtin_amdgcn_mfma_f32_16x16x32_bf16(af[mi], bfv[ni], acc[mi][ni], 0, 0, 0);
        }
    }

    #pragma unroll
    for (int mi = 0; mi < 4; ++mi) {
        #pragma unroll
        for (int ni = 0; ni < 4; ++ni) {
            #pragma unroll
            for (int reg = 0; reg < 4; ++reg) {
                float v = acc[mi][ni][reg];
                if (mode == 2) {
                    int f   = n0 + wn + mi * 16 + quad * 4 + reg;
                    int tok = m0 + wm + ni * 16 + l16;
                    int t = tok & (T_SEQ - 1), b = tok >> 11;
                    int h = f >> 6, dk = f & 63;
                    vout[(((size_t)b * NH + h) * DKD + dk) * T_SEQ + t] = (bf16_t)v;
                } else {
                    int row = m0 + wm + mi * 16 + quad * 4 + reg;
                    int col = n0 + wn + ni * 16 + l16;
                    if (mode == 3) {
                        fout[(size_t)row * D_MODEL + col] = v;
                    } else {
                        int t = row & (T_SEQ - 1), b = row >> 11;
                        int h = col >> 6, dk = col & 63;
                        float vp = __shfl_xor(v, 1);
                        int fi = dk >> 1;
                        float c = cost[t * 32 + fi], s = sint[t * 32 + fi];
                        float r = (dk & 1) ? (vp * s + v * c) : (v * c - vp * s);
                        if (mode == 0) r *= Q_SCALE;   // fold 1/sqrt(dk)*log2e into Q
                        bf16_t* dst = (mode == 0) ? qout : kout;
                        dst[(((size_t)b * NH + h) * T_SEQ + t) * DKD + dk] = (bf16_t)r;
                    }
                }
            }
        }
    }
}

__global__ __launch_bounds__(256) void gemm_qkv(
    const bf16_t* __restrict__ A,
    const bf16_t* __restrict__ W0, const bf16_t* __restrict__ W1, const bf16_t* __restrict__ W2,
    bf16_t* __restrict__ qout, bf16_t* __restrict__ kout, bf16_t* __restrict__ vout,
    const float* __restrict__ cost, const float* __restrict__ sint)
{
    const int mode = blockIdx.z;
    const bf16_t* W = (mode == 1) ? W1 : (mode == 2) ? W2 : W0;
    gemm_body(mode, A, W, qout, kout, vout, cost, sint, nullptr);
}

__global__ __launch_bounds__(256) void gemm_out(
    const bf16_t* __restrict__ A, const bf16_t* __restrict__ W,
    float* __restrict__ fout)
{
    gemm_body(3, A, W, nullptr, nullptr, nullptr, nullptr, nullptr, fout);
}

// ---------------- flash attention: key-split x4 + max-free softmax ----------------
// 256-thread block = 4 waves sharing one 32-query range; wave w handles key
// tiles kt ≡ w (mod 4). Fixed-shift softmax (P=exp2(s), no running max) makes
// partial (O,l) combine a PURE SUM -> one LDS combine + single barrier.
__global__ __launch_bounds__(256, 2) void attn_kernel(
    const bf16_t* __restrict__ Q, const bf16_t* __restrict__ Kb,
    const bf16_t* __restrict__ Vt, bf16_t* __restrict__ O)
{
    __shared__ float Ocomb[3][2][4][4][16][4];  // [w-1][j][di][quad][l16][reg]
    __shared__ float Lcomb[3][2][64];           // [w-1][j][lane]
    __shared__ bf16_t Pw[4][16 * 72];           // per-wave P^T buffer
    const int tid = threadIdx.x;
    const int wave = tid >> 6, lane = tid & 63;
    const int quad = lane >> 4, l16 = lane & 15;
    const int bh = blockIdx.x;
    const int qb = 63 - (int)blockIdx.y;        // heavy q-blocks dispatch first
    const int qw = qb * 32;

    const bf16_t* kbase = Kb + (size_t)bh * T_SEQ * DKD;
    const bf16_t* vbase = Vt + (size_t)bh * DKD * T_SEQ;

    bf16x8 qf[2][2];
    #pragma unroll
    for (int j = 0; j < 2; ++j) {
        const bf16_t* qp = Q + ((size_t)bh * T_SEQ + qw + j * 16 + l16) * DKD;
        qf[j][0] = *(const bf16x8*)(qp + quad * 8);
        qf[j][1] = *(const bf16x8*)(qp + 32 + quad * 8);
    }
    const f32x4 fzero = {0.f, 0.f, 0.f, 0.f};
    f32x4 oacc[2][4];
    #pragma unroll
    for (int j = 0; j < 2; ++j)
        #pragma unroll
        for (int i = 0; i < 4; ++i) oacc[j][i] = fzero;
    float lsum[2] = {0.f, 0.f};

    const int nkt = (qw + 95) >> 6;   // causal 64-key tile count for this q-block

    bf16x8 kcur[4][2], knxt[4][2], vcur[4][2];
    #pragma unroll
    for (int fi = 0; fi < 4; ++fi) {
        const bf16_t* kr = kbase + (size_t)(wave * 64 + fi * 16 + l16) * DKD + quad * 8;
        kcur[fi][0] = *(const bf16x8*)(kr);
        kcur[fi][1] = *(const bf16x8*)(kr + 32);
    }

    for (int kt = wave; kt < nkt; kt += 4) {
        const int k0 = kt * 64;
        #pragma unroll
        for (int di = 0; di < 4; ++di) {
            const bf16_t* vr = vbase + (size_t)(di * 16 + l16) * T_SEQ + k0 + quad * 8;
            vcur[di][0] = *(const bf16x8*)(vr);
            vcur[di][1] = *(const bf16x8*)(vr + 32);
        }
        if (kt + 4 < nkt) {
            #pragma unroll
            for (int fi = 0; fi < 4; ++fi) {
                const bf16_t* kr = kbase + (size_t)((kt + 4) * 64 + fi * 16 + l16) * DKD + quad * 8;
                knxt[fi][0] = *(const bf16x8*)(kr);
                knxt[fi][1] = *(const bf16x8*)(kr + 32);
            }
        }

        #pragma unroll
        for (int j = 0; j < 2; ++j) {
            if (k0 > qw + j * 16 + 15) continue;
            const int qcol = qw + j * 16 + l16;
            f32x4 s[4];
            #pragma unroll
            for (int fi = 0; fi < 4; ++fi) {
                f32x4 z = fzero;
                z = __builtin_amdgcn_mfma_f32_16x16x32_bf16(kcur[fi][0], qf[j][0], z, 0, 0, 0);
                z = __builtin_amdgcn_mfma_f32_16x16x32_bf16(kcur[fi][1], qf[j][1], z, 0, 0, 0);
                s[fi] = z;
            }
            if (k0 + 63 > qw + j * 16) {
                #pragma unroll
                for (int fi = 0; fi < 4; ++fi)
                    #pragma unroll
                    for (int reg = 0; reg < 4; ++reg) {
                        int key = k0 + fi * 16 + quad * 4 + reg;
                        s[fi][reg] = (key > qcol) ? -__builtin_inff() : s[fi][reg];
                    }
            }
            float sm = 0.f;
            #pragma unroll
            for (int fi = 0; fi < 4; ++fi)
                #pragma unroll
                for (int reg = 0; reg < 4; ++reg) {
                    float p = __builtin_amdgcn_exp2f(s[fi][reg]);
                    s[fi][reg] = p;
                    sm += p;
                }
            lsum[j] += sm;

            bf16_t* pw = &Pw[wave][0];
            #pragma unroll
            for (int fi = 0; fi < 4; ++fi) {
                union { bf16_t h[4]; unsigned long long u64; } pk;
                pk.h[0] = (bf16_t)s[fi][0]; pk.h[1] = (bf16_t)s[fi][1];
                pk.h[2] = (bf16_t)s[fi][2]; pk.h[3] = (bf16_t)s[fi][3];
                *(unsigned long long*)(pw + l16 * 72 + fi * 16 + quad * 4) = pk.u64;
            }
            bf16x8 pf[2];
            pf[0] = *(const bf16x8*)(pw + l16 * 72 + quad * 8);
            pf[1] = *(const bf16x8*)(pw + l16 * 72 + 32 + quad * 8);

            #pragma unroll
            for (int di = 0; di < 4; ++di) {
                oacc[j][di] = __builtin_amdgcn_mfma_f32_16x16x32_bf16(vcur[di][0], pf[0], oacc[j][di], 0, 0, 0);
                oacc[j][di] = __builtin_amdgcn_mfma_f32_16x16x32_bf16(vcur[di][1], pf[1], oacc[j][di], 0, 0, 0);
            }
        }

        if (kt + 4 < nkt) {
            #pragma unroll
            for (int fi = 0; fi < 4; ++fi) {
                kcur[fi][0] = knxt[fi][0];
                kcur[fi][1] = knxt[fi][1];
            }
        }
    }

    // combine partials: waves 1-3 write (O,l) to LDS; barrier; wave 0 sums
    if (wave > 0) {
        #pragma unroll
        for (int j = 0; j < 2; ++j) {
            #pragma unroll
            for (int di = 0; di < 4; ++di)
                *(f32x4*)&Ocomb[wave - 1][j][di][quad][l16][0] = oacc[j][di];
            Lcomb[wave - 1][j][lane] = lsum[j];
        }
    }
    __syncthreads();
    if (wave != 0) return;

    #pragma unroll
    for (int j = 0; j < 2; ++j) {
        #pragma unroll
        for (int w = 0; w < 3; ++w) {
            #pragma unroll
            for (int di = 0; di < 4; ++di) {
                f32x4 p = *(const f32x4*)&Ocomb[w][j][di][quad][l16][0];
                #pragma unroll
                for (int reg = 0; reg < 4; ++reg) oacc[j][di][reg] += p[reg];
            }
            lsum[j] += Lcomb[w][j][lane];
        }
    }

    const int b = bh >> 4, h = bh & 15;
    #pragma unroll
    for (int j = 0; j < 2; ++j) {
        float l = lsum[j];
        l += __shfl_xor(l, 16);
        l += __shfl_xor(l, 32);
        float rl = 1.0f / l;
        int q = qw + j * 16 + l16;
        #pragma unroll
        for (int di = 0; di < 4; ++di) {
            union { bf16_t hh[4]; unsigned long long u64; } ok;
            #pragma unroll
            for (int reg = 0; reg < 4; ++reg) ok.hh[reg] = (bf16_t)(oacc[j][di][reg] * rl);
            int d = di * 16 + quad * 4;
            *(unsigned long long*)(O + ((size_t)b * T_SEQ + q) * D_MODEL + h * DKD + d) = ok.u64;
        }
    }
}

extern "C" void kernel_launch(void* const* d_in, const int* in_sizes, int n_in,
                              void* d_out, int out_size, void* d_ws, size_t ws_size,
                              hipStream_t stream)
{
    const float* x  = (const float*)d_in[0];
    const float* wq = (const float*)d_in[1];
    const float* wk = (const float*)d_in[2];
    const float* wv = (const float*)d_in[3];
    const float* wo = (const float*)d_in[4];
    float* out = (float*)d_out;

    char* ws = (char*)d_ws;
    size_t off = 0;
    auto alloc = [&](size_t bytes) -> void* {
        void* p = ws + off; off += (bytes + 255) & ~(size_t)255; return p;
    };
    bf16_t* xb   = (bf16_t*)alloc((size_t)X_ELEMS * 2);
    bf16_t* wqb  = (bf16_t*)alloc((size_t)W_ELEMS * 2);
    bf16_t* wkb  = (bf16_t*)alloc((size_t)W_ELEMS * 2);
    bf16_t* wvb  = (bf16_t*)alloc((size_t)W_ELEMS * 2);
    bf16_t* wob  = (bf16_t*)alloc((size_t)W_ELEMS * 2);
    bf16_t* qb   = (bf16_t*)alloc((size_t)X_ELEMS * 2);
    bf16_t* kb   = (bf16_t*)alloc((size_t)X_ELEMS * 2);
    bf16_t* vtb  = (bf16_t*)alloc((size_t)X_ELEMS * 2);
    bf16_t* ob   = (bf16_t*)alloc((size_t)X_ELEMS * 2);
    float*  cost = (float*)alloc((size_t)T_SEQ * 32 * 4);
    float*  sint = (float*)alloc((size_t)T_SEQ * 32 * 4);

    convert_kernel<<<8192, 256, 0, stream>>>(x, wq, wk, wv, wo, xb, wqb, wkb, wvb, wob);
    rope_kernel<<<256, 256, 0, stream>>>(cost, sint);
    gemm_qkv<<<dim3(32, 8, 3), 256, 0, stream>>>(xb, wqb, wkb, wvb, qb, kb, vtb, cost, sint);
    attn_kernel<<<dim3(32, 64), 256, 0, stream>>>(qb, kb, vtb, ob);
    gemm_out<<<dim3(32, 8, 1), 256, 0, stream>>>(ob, wob, out);
}